// Round 7
// baseline (358.442 us; speedup 1.0000x reference)
//
#include <hip/hip_runtime.h>
#include <math.h>

#define NN 100000
#define DD 128
#define CC 16
#define SS 16
#define EE 3200000
#define KK 64
#define NIT 4
#define CNT_STRIDE 32   // pad class counters 128B apart
#define NB 32           // stage-A slices per class
#define SLMAX 4096      // max stage-A slice (pow2 >= ceil(NN/NB)=3125)
#define MM (NB * KK)    // stage-B merge size = 2048
#define EBLK 2048       // grid-stride blocks for edge scan
#define INF_STAMP 0x7fffffff

typedef unsigned long long ull;

// order-preserving double -> uint64 bijection (and exact inverse)
__device__ inline ull ordkey(double d) {
    long long b = __double_as_longlong(d);
    return (b < 0) ? ~(ull)b : ((ull)b | 0x8000000000000000ULL);
}
__device__ inline double keyord(ull u) {
    long long b = (u & 0x8000000000000000ULL)
                    ? (long long)(u & 0x7FFFFFFFFFFFFFFFULL)
                    : (long long)~u;
    return __longlong_as_double(b);
}
// total order: "a earlier than b" == key desc, node asc (== lax.top_k order)
__device__ inline bool gt(ull ka, int na, ull kb, int nb) {
    return (ka > kb) || (ka == kb && na < nb);
}

// in-wave bitonic sort of 64 (key,node) pairs, descending by gt. zero barriers.
__device__ inline void wsort64(ull& k, int& n, int lane) {
    for (int k2 = 2; k2 <= 64; k2 <<= 1) {
        for (int j = k2 >> 1; j; j >>= 1) {
            ull ok = __shfl_xor(k, j, 64);
            int on = __shfl_xor(n, j, 64);
            bool isLow = (lane & j) == 0;
            bool d = (k2 == 64) || ((lane & k2) == 0);
            bool wantMax = (d == isLow);
            if (wantMax == gt(ok, on, k, n)) { k = ok; n = on; }
        }
    }
}
// in-wave bitonic merge (input bitonic), descending by gt
__device__ inline void wmerge64(ull& k, int& n, int lane) {
    for (int j = 32; j; j >>= 1) {
        ull ok = __shfl_xor(k, j, 64);
        int on = __shfl_xor(n, j, 64);
        bool wantMax = (lane & j) == 0;
        if (wantMax == gt(ok, on, k, n)) { k = ok; n = on; }
    }
}

// ---------- init: state reset + seed marking fused (no es pass; norms live in k_cand) ----------

__global__ __launch_bounds__(256)
void k_init(const int* __restrict__ seeds, int* __restrict__ known,
            unsigned* __restrict__ cate, unsigned* __restrict__ nbr,
            unsigned* __restrict__ done) {
    __shared__ int sd[CC * SS];
    int tid = threadIdx.x;
    if (tid < CC * SS) sd[tid] = seeds[tid];
    __syncthreads();
    if (blockIdx.x == 0 && tid < CC) done[tid] = 0;   // merge-flag reset
    int wave = tid >> 6, lane = tid & 63;
    int n = blockIdx.x * 4 + wave;
    if (n >= NN) return;
    // does this node appear in the seed list? (4 entries per lane covers all 256)
    unsigned m = 0;
    #pragma unroll
    for (int e = lane; e < CC * SS; e += 64)
        if (sd[e] == n) m |= 1u << (e / SS);
    for (int o = 32; o > 0; o >>= 1) m |= __shfl_xor(m, o, 64);
    if (lane == 0) {
        known[n] = m ? 0 : INF_STAMP;   // seeds known since iteration 0
        cate[n] = m;
        nbr[n] = 0;
    }
}

// ------------- fused: memory step (blocks 0..15) + edge pass (rest, grid-stride) -------------
// independent within an iteration: mem reads es/seeds/last/hx, edge reads cate -> nbr

__global__ __launch_bounds__(256)
void k_memedge(const float* __restrict__ es, const float* __restrict__ Wm,
               const int* __restrict__ seeds, const int* __restrict__ last,
               double* __restrict__ hx, double* __restrict__ hxn,
               float* __restrict__ out, int* __restrict__ cnt,
               const int* __restrict__ edge, const unsigned* __restrict__ cate,
               unsigned* __restrict__ nbr, int t) {
    __shared__ float  inp[KK][DD + 1];   // pad: conflict-free column reads
    __shared__ int    rowS[KK];
    __shared__ double q[DD];
    __shared__ double lg[KK];
    __shared__ double sr[KK];
    __shared__ double pre[DD];
    __shared__ double red[DD];
    int tid = threadIdx.x;

    if (blockIdx.x >= CC) {
        // ---- edge branch: nbr[dst] |= cate[src] ----
        for (long e = (long)(blockIdx.x - CC) * 256 + tid; e < EE;
             e += (long)EBLK * 256) {
            int s = edge[e];
            unsigned m = cate[s];
            if (m) atomicOr(&nbr[edge[EE + e]], m);
        }
        return;
    }

    // ---- memory-step branch (block-uniform; barriers legal) ----
    int c = blockIdx.x;
    if (tid == 0) cnt[c * CNT_STRIDE] = 0;     // fused counter reset
    int k = (t == 0) ? SS : KK;
    if (tid < KK) {
        lg[tid] = -1.0e308;
        if (tid < k) rowS[tid] = (t == 0) ? seeds[c * SS + tid] : last[c * KK + tid];
    }
    __syncthreads();
    for (int i = tid; i < k * DD; i += 256)
        inp[i >> 7][i & 127] = es[(long)rowS[i >> 7] * DD + (i & 127)];
    __syncthreads();
    if (tid < DD) {
        if (t == 0) {
            double s = 0;
            for (int j = 0; j < k; ++j) s += (double)inp[j][tid];
            q[tid] = s / (double)k;
        } else {
            q[tid] = hx[c * DD + tid];
        }
    }
    __syncthreads();
    if (tid < k) {
        double s = 0;
        for (int i = 0; i < DD; ++i) s += (double)inp[tid][i] * q[i];
        lg[tid] = s / sqrt((double)DD);
    }
    __syncthreads();
    if (tid < KK) sr[tid] = lg[tid];
    __syncthreads();
    for (int st = 32; st > 0; st >>= 1) {
        if (tid < st) sr[tid] = fmax(sr[tid], sr[tid + st]);
        __syncthreads();
    }
    double mx = sr[0];
    __syncthreads();
    if (tid < KK) {
        double e = (tid < k) ? exp(lg[tid] - mx) : 0.0;
        lg[tid] = e; sr[tid] = e;
    }
    __syncthreads();
    for (int st = 32; st > 0; st >>= 1) {
        if (tid < st) sr[tid] += sr[tid + st];
        __syncthreads();
    }
    double sm = sr[0];
    __syncthreads();
    if (tid < KK) lg[tid] /= sm;
    __syncthreads();
    if (tid < DD) {
        double ctx = 0;
        for (int j = 0; j < k; ++j) ctx += lg[j] * (double)inp[j][tid];
        pre[tid] = (t == 0) ? ctx : (ctx + q[tid]);
    }
    __syncthreads();
    double h = 0;
    if (tid < DD) {
        for (int i = 0; i < DD; ++i) h += pre[i] * (double)Wm[i * DD + tid];
        h = tanh(h);
        red[tid] = h * h;
    }
    __syncthreads();
    for (int st = 64; st > 0; st >>= 1) {
        if (tid < st) red[tid] += red[tid + st];
        __syncthreads();
    }
    if (tid < DD) {
        double inv = 1.0 / (sqrt(red[0]) + 1e-8);
        hx[c * DD + tid] = h;
        hxn[c * DD + tid] = h * inv;
        out[2 * NIT * CC * KK + t * CC * DD + c * DD + tid] = (float)h;  // hxes
    }
}

// ---------- candidate scoring: block-aggregated, thread-per-pair, norm fused (R4-exact) ----------

__global__ __launch_bounds__(256)
void k_cand(const float* __restrict__ es,
            const int* __restrict__ known, const unsigned* __restrict__ nbr,
            const double* __restrict__ hxn,
            int* __restrict__ cnt, int* __restrict__ cidx,
            ull* __restrict__ ckey, int cap, int t) {
    __shared__ int    pair[256 * 16];
    __shared__ short  prank[256 * 16];
    __shared__ double hxnL[CC * 129];
    __shared__ int    lcnt[CC];
    __shared__ int    base[CC];
    __shared__ int    npair;
    int tid = threadIdx.x;

    for (int i = tid; i < CC * DD; i += 256)
        hxnL[(i >> 7) * 129 + (i & 127)] = hxn[i];
    if (tid < CC) lcnt[tid] = 0;
    if (tid == 0) npair = 0;
    __syncthreads();

    int n = blockIdx.x * 256 + tid;
    unsigned m = 0;
    if (n < NN && known[n] > t) m = nbr[n];   // stamp > t  <=>  unknown at iter t
    while (m) {
        int c = __ffs(m) - 1;
        m &= m - 1;
        int r = atomicAdd(&lcnt[c], 1);
        int p = atomicAdd(&npair, 1);
        pair[p] = (n << 4) | c;
        prank[p] = (short)r;
    }
    __syncthreads();

    if (tid < CC && lcnt[tid] > 0)
        base[tid] = atomicAdd(&cnt[tid * CNT_STRIDE], lcnt[tid]);
    __syncthreads();

    int np = npair;
    for (int t2 = tid; t2 < np; t2 += 256) {
        int pk = pair[t2];
        int nn = pk >> 4, c = pk & 15;
        const float4* row = (const float4*)(es + (long)nn * DD);
        const double* h = &hxnL[c * 129];
        double s = 0, p2 = 0;
        #pragma unroll
        for (int i = 0; i < 32; ++i) {
            float4 v = row[i];
            double vx = v.x, vy = v.y, vz = v.z, vw = v.w;
            s  += vx * h[4 * i + 0] + vy * h[4 * i + 1]
                + vz * h[4 * i + 2] + vw * h[4 * i + 3];
            p2 += vx * vx + vy * vy + vz * vz + vw * vw;
        }
        int pos = base[c] + (int)prank[t2];
        if (pos < cap) {
            cidx[(long)c * cap + pos] = nn;
            ckey[(long)c * cap + pos] = ordkey(s / (sqrt(p2) + 1e-8));
        }
    }
}

// ---------- fused stage A+B: 512 blocks; last block per class merges + updates ----------
// stage A identical to verified k_top; slice outputs published with device-scope
// atomics; the 32nd-arriving block of each class re-reads all 32 runs and runs the
// verified stage-B merge + update. Removes 4 launches with zero parallelism loss.

__global__ __launch_bounds__(256)
void k_topmerge(const int* __restrict__ cnt, const int* __restrict__ cidx,
                const ull* __restrict__ ckey, int cap,
                ull* __restrict__ tkey, int* __restrict__ tnode,
                unsigned* __restrict__ done,
                int* __restrict__ known, const unsigned* __restrict__ nbr,
                unsigned* __restrict__ cate, int* __restrict__ last,
                float* __restrict__ out, int t) {
    __shared__ ull ks[SLMAX];
    __shared__ int ns[SLMAX];
    __shared__ int iswin;
    int c = blockIdx.x / NB, b = blockIdx.x % NB;
    int tid = threadIdx.x, wave = tid >> 6, lane = tid & 63;
    int count = min(cnt[c * CNT_STRIDE], cap);
    int per = (count + NB - 1) / NB;
    int start = b * per;
    int m = min(per, count - start);
    int sl = 64;
    while (sl < per) sl <<= 1;
    int nruns = sl >> 6;
    // stage A: sort each 64-run inside one wave (registers, no barriers)
    for (int r = wave; r < nruns; r += 4) {
        int i = (r << 6) + lane;
        ull k; int n;
        if (i < m) { k = ckey[(long)c * cap + start + i]; n = cidx[(long)c * cap + start + i]; }
        else       { k = 0ULL; n = 0x7FFFFFFF; }
        wsort64(k, n, lane);
        ks[i] = k; ns[i] = n;
    }
    __syncthreads();
    // merge tree: each pair handled by one wave; winner written over run A
    for (int step = 1; step < nruns; step <<= 1) {
        int npair2 = nruns / (2 * step);
        for (int pr = wave; pr < npair2; pr += 4) {
            int ra = pr * 2 * step, rb = ra + step;
            ull ka = ks[(ra << 6) + lane];       int na = ns[(ra << 6) + lane];
            ull kb = ks[(rb << 6) + 63 - lane];  int nb2 = ns[(rb << 6) + 63 - lane];
            if (gt(kb, nb2, ka, na)) { ka = kb; na = nb2; }   // bitonic split -> winners
            wmerge64(ka, na, lane);
            ks[(ra << 6) + lane] = ka; ns[(ra << 6) + lane] = na;
        }
        __syncthreads();
    }
    // publish slice result with device-scope atomics (cross-XCD coherent, m20)
    if (tid < KK) {
        atomicExch(&tkey[(long)c * MM + b * KK + tid], ks[tid]);
        atomicExch((unsigned*)&tnode[(long)c * MM + b * KK + tid], (unsigned)ns[tid]);
    }
    __syncthreads();    // barrier drains vmcnt: all lanes' publishes complete
    if (tid == 0) {
        __threadfence();
        unsigned old = atomicAdd(&done[c], 1u);
        iswin = (old == NB - 1);
        if (iswin) atomicExch(&done[c], 0u);   // reset for next iteration
    }
    __syncthreads();
    if (!iswin) return;

    // ---- stage B (winner block only): merge 32 runs -> top-64, apply updates ----
    __threadfence();
    for (int i = tid; i < MM; i += 256) {
        ks[i] = atomicOr(&tkey[(long)c * MM + i], 0ULL);           // coherent read
        ns[i] = (int)atomicOr((unsigned*)&tnode[(long)c * MM + i], 0u);
    }
    __syncthreads();
    for (int step = 1; step < NB; step <<= 1) {
        int npair2 = NB / (2 * step);
        for (int pr = wave; pr < npair2; pr += 4) {
            int ra = pr * 2 * step, rb = ra + step;
            ull ka = ks[(ra << 6) + lane];       int na = ns[(ra << 6) + lane];
            ull kb = ks[(rb << 6) + 63 - lane];  int nb2 = ns[(rb << 6) + 63 - lane];
            if (gt(kb, nb2, ka, na)) { ka = kb; na = nb2; }
            wmerge64(ka, na, lane);
            ks[(ra << 6) + lane] = ka; ns[(ra << 6) + lane] = na;
        }
        __syncthreads();
    }
    int nsel = min(count, KK);
    if (tid < KK && tid < nsel) {
        int n = ns[tid];
        out[t * CC * KK + c * KK + tid] = (float)keyord(ks[tid]);     // outs
        out[NIT * CC * KK + t * CC * KK + c * KK + tid] = (float)n;   // exps
        last[c * KK + tid] = n;
        known[n] = t + 1;               // stamp: invisible to this iteration's tests
        atomicOr(&cate[n], 1u << c);
    }
    // fill path (fewer valid than K): lowest-index invalid nodes, prob=-1e9.
    // stamp test (known[n] <= t) sees only pre-iteration state -> race-free vs
    // concurrent t+1 stamps from other classes (matches reference semantics).
    if (tid == 0 && nsel < KK) {
        int r = nsel;
        for (int n = 0; n < NN && r < KK; ++n) {
            bool valid = ((nbr[n] >> c) & 1u) && (known[n] > t);
            if (!valid) {
                out[t * CC * KK + c * KK + r] = -1e9f;
                out[NIT * CC * KK + t * CC * KK + c * KK + r] = (float)n;
                last[c * KK + r] = n;
                known[n] = t + 1;
                atomicOr(&cate[n], 1u << c);
                ++r;
            }
        }
    }
}

// -------------------- host launcher: 13 launches total --------------------

extern "C" void kernel_launch(void* const* d_in, const int* in_sizes, int n_in,
                              void* d_out, int out_size, void* d_ws, size_t ws_size,
                              hipStream_t stream) {
    const float* es    = (const float*)d_in[0];
    const int*   edge  = (const int*)d_in[1];
    const int*   seeds = (const int*)d_in[2];
    const float* W     = (const float*)d_in[3];
    float* out = (float*)d_out;

    char* p = (char*)d_ws;
    auto alloc = [&](size_t bytes) -> char* {
        char* r = p;
        p += (bytes + 255) & ~(size_t)255;
        return r;
    };
    int*      known    = (int*)alloc((size_t)NN * 4);
    unsigned* cate     = (unsigned*)alloc((size_t)NN * 4);
    unsigned* nbr      = (unsigned*)alloc((size_t)NN * 4);
    double*   hx       = (double*)alloc(CC * DD * 8);
    double*   hxn      = (double*)alloc(CC * DD * 8);
    int*      last     = (int*)alloc(CC * KK * 4);
    int*      cnt      = (int*)alloc(CC * CNT_STRIDE * 4);
    ull*      tkey     = (ull*)alloc((size_t)CC * MM * 8);
    int*      tnode    = (int*)alloc((size_t)CC * MM * 4);
    unsigned* done     = (unsigned*)alloc(CC * 4);
    size_t used = (size_t)(p - (char*)d_ws);
    size_t rem = (ws_size > used + 8192) ? (ws_size - used - 8192) : 0;
    long capl = (long)(rem / (CC * 12));
    if (capl > NN) capl = NN;
    if (capl < 1) capl = 1;
    int cap = (int)capl;
    int*    cidx = (int*)alloc((size_t)CC * cap * 4);
    ull*    ckey = (ull*)alloc((size_t)CC * cap * 8);

    k_init<<<(NN + 3) / 4, 256, 0, stream>>>(seeds, known, cate, nbr, done);

    for (int t = 0; t < NIT; ++t) {
        k_memedge<<<CC + EBLK, 256, 0, stream>>>(es, W, seeds, last, hx, hxn, out,
                                                 cnt, edge, cate, nbr, t);
        k_cand<<<(NN + 255) / 256, 256, 0, stream>>>(es, known, nbr, hxn,
                                                     cnt, cidx, ckey, cap, t);
        k_topmerge<<<CC * NB, 256, 0, stream>>>(cnt, cidx, ckey, cap, tkey, tnode,
                                                done, known, nbr, cate, last, out, t);
    }
}

// Round 8
// 332.611 us; speedup vs baseline: 1.0777x; 1.0777x over previous
//
#include <hip/hip_runtime.h>
#include <math.h>

#define NN 100000
#define DD 128
#define CC 16
#define SS 16
#define EE 3200000
#define KK 64
#define NIT 4
#define CNT_STRIDE 32   // pad class counters 128B apart
#define NB 32           // stage-A slices per class
#define SLMAX 4096      // max stage-A slice (pow2 >= ceil(NN/NB)=3125)
#define MM (NB * KK)    // stage-B merge size = 2048
#define EBLK 2048       // grid-stride blocks for edge scan
#define INF_STAMP 0x7fffffff

typedef unsigned long long ull;

// order-preserving double -> uint64 bijection (and exact inverse)
__device__ inline ull ordkey(double d) {
    long long b = __double_as_longlong(d);
    return (b < 0) ? ~(ull)b : ((ull)b | 0x8000000000000000ULL);
}
__device__ inline double keyord(ull u) {
    long long b = (u & 0x8000000000000000ULL)
                    ? (long long)(u & 0x7FFFFFFFFFFFFFFFULL)
                    : (long long)~u;
    return __longlong_as_double(b);
}
// total order: "a earlier than b" == key desc, node asc (== lax.top_k order)
__device__ inline bool gt(ull ka, int na, ull kb, int nb) {
    return (ka > kb) || (ka == kb && na < nb);
}

// in-wave bitonic sort of 64 (key,node) pairs, descending by gt. zero barriers.
__device__ inline void wsort64(ull& k, int& n, int lane) {
    for (int k2 = 2; k2 <= 64; k2 <<= 1) {
        for (int j = k2 >> 1; j; j >>= 1) {
            ull ok = __shfl_xor(k, j, 64);
            int on = __shfl_xor(n, j, 64);
            bool isLow = (lane & j) == 0;
            bool d = (k2 == 64) || ((lane & k2) == 0);
            bool wantMax = (d == isLow);
            if (wantMax == gt(ok, on, k, n)) { k = ok; n = on; }
        }
    }
}
// in-wave bitonic merge (input bitonic), descending by gt
__device__ inline void wmerge64(ull& k, int& n, int lane) {
    for (int j = 32; j; j >>= 1) {
        ull ok = __shfl_xor(k, j, 64);
        int on = __shfl_xor(n, j, 64);
        bool wantMax = (lane & j) == 0;
        if (wantMax == gt(ok, on, k, n)) { k = ok; n = on; }
    }
}

// ---------- init: state reset + seed marking fused (no es pass; norms live in k_cand) ----------

__global__ __launch_bounds__(256)
void k_init(const int* __restrict__ seeds, int* __restrict__ known,
            unsigned* __restrict__ cate, unsigned* __restrict__ nbr,
            unsigned* __restrict__ done) {
    __shared__ int sd[CC * SS];
    int tid = threadIdx.x;
    if (tid < CC * SS) sd[tid] = seeds[tid];
    __syncthreads();
    if (blockIdx.x == 0 && tid < CC) done[tid] = 0;   // merge-flag reset
    int wave = tid >> 6, lane = tid & 63;
    int n = blockIdx.x * 4 + wave;
    if (n >= NN) return;
    // does this node appear in the seed list? (4 entries per lane covers all 256)
    unsigned m = 0;
    #pragma unroll
    for (int e = lane; e < CC * SS; e += 64)
        if (sd[e] == n) m |= 1u << (e / SS);
    for (int o = 32; o > 0; o >>= 1) m |= __shfl_xor(m, o, 64);
    if (lane == 0) {
        known[n] = m ? 0 : INF_STAMP;   // seeds known since iteration 0
        cate[n] = m;
        nbr[n] = 0;
    }
}

// ------------- fused: memory step (blocks 0..15) + edge pass (rest, grid-stride) -------------
// edge pass is INCREMENTAL: only nodes that became known exactly at iteration t
// (known[s]==t) propagate; their cate bits are final by then, and nbr is a
// monotone OR-accumulator, so the union over iterations equals the full rescan.

__global__ __launch_bounds__(256)
void k_memedge(const float* __restrict__ es, const float* __restrict__ Wm,
               const int* __restrict__ seeds, const int* __restrict__ last,
               double* __restrict__ hx, double* __restrict__ hxn,
               float* __restrict__ out, int* __restrict__ cnt,
               const int* __restrict__ edge, const unsigned* __restrict__ cate,
               const int* __restrict__ known, unsigned* __restrict__ nbr, int t) {
    __shared__ float  inp[KK][DD + 1];   // pad: conflict-free column reads
    __shared__ int    rowS[KK];
    __shared__ double q[DD];
    __shared__ double lg[KK];
    __shared__ double sr[KK];
    __shared__ double pre[DD];
    __shared__ double red[DD];
    int tid = threadIdx.x;

    if (blockIdx.x >= CC) {
        // ---- edge branch: nbr[dst] |= cate[src] for newly-known src only ----
        for (long e = (long)(blockIdx.x - CC) * 256 + tid; e < EE;
             e += (long)EBLK * 256) {
            int s = edge[e];
            if (known[s] == t) {                 // became known at iter t-1 (t=0: seeds)
                unsigned m = cate[s];            // final bits, nonzero by construction
                atomicOr(&nbr[edge[EE + e]], m);
            }
        }
        return;
    }

    // ---- memory-step branch (block-uniform; barriers legal) ----
    int c = blockIdx.x;
    if (tid == 0) cnt[c * CNT_STRIDE] = 0;     // fused counter reset
    int k = (t == 0) ? SS : KK;
    if (tid < KK) {
        lg[tid] = -1.0e308;
        if (tid < k) rowS[tid] = (t == 0) ? seeds[c * SS + tid] : last[c * KK + tid];
    }
    __syncthreads();
    for (int i = tid; i < k * DD; i += 256)
        inp[i >> 7][i & 127] = es[(long)rowS[i >> 7] * DD + (i & 127)];
    __syncthreads();
    if (tid < DD) {
        if (t == 0) {
            double s = 0;
            for (int j = 0; j < k; ++j) s += (double)inp[j][tid];
            q[tid] = s / (double)k;
        } else {
            q[tid] = hx[c * DD + tid];
        }
    }
    __syncthreads();
    if (tid < k) {
        double s = 0;
        for (int i = 0; i < DD; ++i) s += (double)inp[tid][i] * q[i];
        lg[tid] = s / sqrt((double)DD);
    }
    __syncthreads();
    if (tid < KK) sr[tid] = lg[tid];
    __syncthreads();
    for (int st = 32; st > 0; st >>= 1) {
        if (tid < st) sr[tid] = fmax(sr[tid], sr[tid + st]);
        __syncthreads();
    }
    double mx = sr[0];
    __syncthreads();
    if (tid < KK) {
        double e = (tid < k) ? exp(lg[tid] - mx) : 0.0;
        lg[tid] = e; sr[tid] = e;
    }
    __syncthreads();
    for (int st = 32; st > 0; st >>= 1) {
        if (tid < st) sr[tid] += sr[tid + st];
        __syncthreads();
    }
    double sm = sr[0];
    __syncthreads();
    if (tid < KK) lg[tid] /= sm;
    __syncthreads();
    if (tid < DD) {
        double ctx = 0;
        for (int j = 0; j < k; ++j) ctx += lg[j] * (double)inp[j][tid];
        pre[tid] = (t == 0) ? ctx : (ctx + q[tid]);
    }
    __syncthreads();
    double h = 0;
    if (tid < DD) {
        for (int i = 0; i < DD; ++i) h += pre[i] * (double)Wm[i * DD + tid];
        h = tanh(h);
        red[tid] = h * h;
    }
    __syncthreads();
    for (int st = 64; st > 0; st >>= 1) {
        if (tid < st) red[tid] += red[tid + st];
        __syncthreads();
    }
    if (tid < DD) {
        double inv = 1.0 / (sqrt(red[0]) + 1e-8);
        hx[c * DD + tid] = h;
        hxn[c * DD + tid] = h * inv;
        out[2 * NIT * CC * KK + t * CC * DD + c * DD + tid] = (float)h;  // hxes
    }
}

// ---------- candidate scoring: block-aggregated, thread-per-pair, norm fused (R4-exact) ----------

__global__ __launch_bounds__(256)
void k_cand(const float* __restrict__ es,
            const int* __restrict__ known, const unsigned* __restrict__ nbr,
            const double* __restrict__ hxn,
            int* __restrict__ cnt, int* __restrict__ cidx,
            ull* __restrict__ ckey, int cap, int t) {
    __shared__ int    pair[256 * 16];
    __shared__ short  prank[256 * 16];
    __shared__ double hxnL[CC * 129];
    __shared__ int    lcnt[CC];
    __shared__ int    base[CC];
    __shared__ int    npair;
    int tid = threadIdx.x;

    for (int i = tid; i < CC * DD; i += 256)
        hxnL[(i >> 7) * 129 + (i & 127)] = hxn[i];
    if (tid < CC) lcnt[tid] = 0;
    if (tid == 0) npair = 0;
    __syncthreads();

    int n = blockIdx.x * 256 + tid;
    unsigned m = 0;
    if (n < NN && known[n] > t) m = nbr[n];   // stamp > t  <=>  unknown at iter t
    while (m) {
        int c = __ffs(m) - 1;
        m &= m - 1;
        int r = atomicAdd(&lcnt[c], 1);
        int p = atomicAdd(&npair, 1);
        pair[p] = (n << 4) | c;
        prank[p] = (short)r;
    }
    __syncthreads();

    if (tid < CC && lcnt[tid] > 0)
        base[tid] = atomicAdd(&cnt[tid * CNT_STRIDE], lcnt[tid]);
    __syncthreads();

    int np = npair;
    for (int t2 = tid; t2 < np; t2 += 256) {
        int pk = pair[t2];
        int nn = pk >> 4, c = pk & 15;
        const float4* row = (const float4*)(es + (long)nn * DD);
        const double* h = &hxnL[c * 129];
        double s = 0, p2 = 0;
        #pragma unroll
        for (int i = 0; i < 32; ++i) {
            float4 v = row[i];
            double vx = v.x, vy = v.y, vz = v.z, vw = v.w;
            s  += vx * h[4 * i + 0] + vy * h[4 * i + 1]
                + vz * h[4 * i + 2] + vw * h[4 * i + 3];
            p2 += vx * vx + vy * vy + vz * vz + vw * vw;
        }
        int pos = base[c] + (int)prank[t2];
        if (pos < cap) {
            cidx[(long)c * cap + pos] = nn;
            ckey[(long)c * cap + pos] = ordkey(s / (sqrt(p2) + 1e-8));
        }
    }
}

// ---------- fused stage A+B: FENCE-FREE. all transfer via device-scope atomics. ----------
// producers: atomicExch publish; __syncthreads drains vmcnt (release); arrival-add.
// winner (32nd arriver): atomic reads (acquire at device-coherent point), merge, update.

__global__ __launch_bounds__(256)
void k_topmerge(const int* __restrict__ cnt, const int* __restrict__ cidx,
                const ull* __restrict__ ckey, int cap,
                ull* __restrict__ tkey, int* __restrict__ tnode,
                unsigned* __restrict__ done,
                int* __restrict__ known, const unsigned* __restrict__ nbr,
                unsigned* __restrict__ cate, int* __restrict__ last,
                float* __restrict__ out, int t) {
    __shared__ ull ks[SLMAX];
    __shared__ int ns[SLMAX];
    __shared__ int iswin;
    int c = blockIdx.x / NB, b = blockIdx.x % NB;
    int tid = threadIdx.x, wave = tid >> 6, lane = tid & 63;
    int count = min(cnt[c * CNT_STRIDE], cap);
    int per = (count + NB - 1) / NB;
    int start = b * per;
    int m = min(per, count - start);
    int sl = 64;
    while (sl < per) sl <<= 1;
    int nruns = sl >> 6;
    // stage A: sort each 64-run inside one wave (registers, no barriers)
    for (int r = wave; r < nruns; r += 4) {
        int i = (r << 6) + lane;
        ull k; int n;
        if (i < m) { k = ckey[(long)c * cap + start + i]; n = cidx[(long)c * cap + start + i]; }
        else       { k = 0ULL; n = 0x7FFFFFFF; }
        wsort64(k, n, lane);
        ks[i] = k; ns[i] = n;
    }
    __syncthreads();
    // merge tree: each pair handled by one wave; winner written over run A
    for (int step = 1; step < nruns; step <<= 1) {
        int npair2 = nruns / (2 * step);
        for (int pr = wave; pr < npair2; pr += 4) {
            int ra = pr * 2 * step, rb = ra + step;
            ull ka = ks[(ra << 6) + lane];       int na = ns[(ra << 6) + lane];
            ull kb = ks[(rb << 6) + 63 - lane];  int nb2 = ns[(rb << 6) + 63 - lane];
            if (gt(kb, nb2, ka, na)) { ka = kb; na = nb2; }   // bitonic split -> winners
            wmerge64(ka, na, lane);
            ks[(ra << 6) + lane] = ka; ns[(ra << 6) + lane] = na;
        }
        __syncthreads();
    }
    // publish slice result with device-scope atomics (cross-XCD coherent, m20). NO fences.
    if (tid < KK) {
        atomicExch(&tkey[(long)c * MM + b * KK + tid], ks[tid]);
        atomicExch((unsigned*)&tnode[(long)c * MM + b * KK + tid], (unsigned)ns[tid]);
    }
    __syncthreads();    // drains vmcnt for all 256 threads: publishes globally complete
    if (tid == 0) {
        unsigned old = atomicAdd(&done[c], 1u);
        iswin = (old == NB - 1);
        if (iswin) atomicExch(&done[c], 0u);   // reset for next iteration
    }
    __syncthreads();
    if (!iswin) return;

    // ---- stage B (winner block only): merge 32 runs -> top-64, apply updates ----
    for (int i = tid; i < MM; i += 256) {
        ks[i] = atomicOr(&tkey[(long)c * MM + i], 0ULL);           // coherent read
        ns[i] = (int)atomicOr((unsigned*)&tnode[(long)c * MM + i], 0u);
    }
    __syncthreads();
    for (int step = 1; step < NB; step <<= 1) {
        int npair2 = NB / (2 * step);
        for (int pr = wave; pr < npair2; pr += 4) {
            int ra = pr * 2 * step, rb = ra + step;
            ull ka = ks[(ra << 6) + lane];       int na = ns[(ra << 6) + lane];
            ull kb = ks[(rb << 6) + 63 - lane];  int nb2 = ns[(rb << 6) + 63 - lane];
            if (gt(kb, nb2, ka, na)) { ka = kb; na = nb2; }
            wmerge64(ka, na, lane);
            ks[(ra << 6) + lane] = ka; ns[(ra << 6) + lane] = na;
        }
        __syncthreads();
    }
    int nsel = min(count, KK);
    if (tid < KK && tid < nsel) {
        int n = ns[tid];
        out[t * CC * KK + c * KK + tid] = (float)keyord(ks[tid]);     // outs
        out[NIT * CC * KK + t * CC * KK + c * KK + tid] = (float)n;   // exps
        last[c * KK + tid] = n;
        known[n] = t + 1;               // stamp: t+1 > t, so concurrent adds stay "unknown at t"
        atomicOr(&cate[n], 1u << c);
    }
    // fill path (fewer valid than K): lowest-index invalid nodes, prob=-1e9.
    if (tid == 0 && nsel < KK) {
        int r = nsel;
        for (int n = 0; n < NN && r < KK; ++n) {
            bool valid = ((nbr[n] >> c) & 1u) && (known[n] > t);
            if (!valid) {
                out[t * CC * KK + c * KK + r] = -1e9f;
                out[NIT * CC * KK + t * CC * KK + c * KK + r] = (float)n;
                last[c * KK + r] = n;
                known[n] = t + 1;
                atomicOr(&cate[n], 1u << c);
                ++r;
            }
        }
    }
}

// -------------------- host launcher: 13 launches total --------------------

extern "C" void kernel_launch(void* const* d_in, const int* in_sizes, int n_in,
                              void* d_out, int out_size, void* d_ws, size_t ws_size,
                              hipStream_t stream) {
    const float* es    = (const float*)d_in[0];
    const int*   edge  = (const int*)d_in[1];
    const int*   seeds = (const int*)d_in[2];
    const float* W     = (const float*)d_in[3];
    float* out = (float*)d_out;

    char* p = (char*)d_ws;
    auto alloc = [&](size_t bytes) -> char* {
        char* r = p;
        p += (bytes + 255) & ~(size_t)255;
        return r;
    };
    int*      known    = (int*)alloc((size_t)NN * 4);
    unsigned* cate     = (unsigned*)alloc((size_t)NN * 4);
    unsigned* nbr      = (unsigned*)alloc((size_t)NN * 4);
    double*   hx       = (double*)alloc(CC * DD * 8);
    double*   hxn      = (double*)alloc(CC * DD * 8);
    int*      last     = (int*)alloc(CC * KK * 4);
    int*      cnt      = (int*)alloc(CC * CNT_STRIDE * 4);
    ull*      tkey     = (ull*)alloc((size_t)CC * MM * 8);
    int*      tnode    = (int*)alloc((size_t)CC * MM * 4);
    unsigned* done     = (unsigned*)alloc(CC * 4);
    size_t used = (size_t)(p - (char*)d_ws);
    size_t rem = (ws_size > used + 8192) ? (ws_size - used - 8192) : 0;
    long capl = (long)(rem / (CC * 12));
    if (capl > NN) capl = NN;
    if (capl < 1) capl = 1;
    int cap = (int)capl;
    int*    cidx = (int*)alloc((size_t)CC * cap * 4);
    ull*    ckey = (ull*)alloc((size_t)CC * cap * 8);

    k_init<<<(NN + 3) / 4, 256, 0, stream>>>(seeds, known, cate, nbr, done);

    for (int t = 0; t < NIT; ++t) {
        k_memedge<<<CC + EBLK, 256, 0, stream>>>(es, W, seeds, last, hx, hxn, out,
                                                 cnt, edge, cate, known, nbr, t);
        k_cand<<<(NN + 255) / 256, 256, 0, stream>>>(es, known, nbr, hxn,
                                                     cnt, cidx, ckey, cap, t);
        k_topmerge<<<CC * NB, 256, 0, stream>>>(cnt, cidx, ckey, cap, tkey, tnode,
                                                done, known, nbr, cate, last, out, t);
    }
}

// Round 9
// 303.393 us; speedup vs baseline: 1.1814x; 1.0963x over previous
//
#include <hip/hip_runtime.h>
#include <math.h>

#define NN 100000
#define DD 128
#define CC 16
#define SS 16
#define EE 3200000
#define KK 64
#define NIT 4
#define CNT_STRIDE 32   // pad class counters 128B apart
#define NB 32           // stage-A slices per class
#define SLMAX 4096      // max stage-A slice (pow2 >= ceil(NN/NB)=3125)
#define MM (NB * KK)    // stage-B merge size = 2048
#define EBLK 2048       // grid-stride blocks for edge scan
#define INF_STAMP 0x7fffffff

typedef unsigned long long ull;

// order-preserving double -> uint64 bijection (and exact inverse)
__device__ inline ull ordkey(double d) {
    long long b = __double_as_longlong(d);
    return (b < 0) ? ~(ull)b : ((ull)b | 0x8000000000000000ULL);
}
__device__ inline double keyord(ull u) {
    long long b = (u & 0x8000000000000000ULL)
                    ? (long long)(u & 0x7FFFFFFFFFFFFFFFULL)
                    : (long long)~u;
    return __longlong_as_double(b);
}
// total order: "a earlier than b" == key desc, node asc (== lax.top_k order)
__device__ inline bool gt(ull ka, int na, ull kb, int nb) {
    return (ka > kb) || (ka == kb && na < nb);
}

// in-wave bitonic sort of 64 (key,node) pairs, descending by gt. zero barriers.
__device__ inline void wsort64(ull& k, int& n, int lane) {
    for (int k2 = 2; k2 <= 64; k2 <<= 1) {
        for (int j = k2 >> 1; j; j >>= 1) {
            ull ok = __shfl_xor(k, j, 64);
            int on = __shfl_xor(n, j, 64);
            bool isLow = (lane & j) == 0;
            bool d = (k2 == 64) || ((lane & k2) == 0);
            bool wantMax = (d == isLow);
            if (wantMax == gt(ok, on, k, n)) { k = ok; n = on; }
        }
    }
}
// in-wave bitonic merge (input bitonic), descending by gt
__device__ inline void wmerge64(ull& k, int& n, int lane) {
    for (int j = 32; j; j >>= 1) {
        ull ok = __shfl_xor(k, j, 64);
        int on = __shfl_xor(n, j, 64);
        bool wantMax = (lane & j) == 0;
        if (wantMax == gt(ok, on, k, n)) { k = ok; n = on; }
    }
}

// ---------- init: state reset + seed marking fused (no es pass; norms live in k_cand) ----------

__global__ __launch_bounds__(256)
void k_init(const int* __restrict__ seeds, int* __restrict__ known,
            unsigned* __restrict__ cate, unsigned* __restrict__ nbr) {
    __shared__ int sd[CC * SS];
    int tid = threadIdx.x;
    if (tid < CC * SS) sd[tid] = seeds[tid];
    __syncthreads();
    int wave = tid >> 6, lane = tid & 63;
    int n = blockIdx.x * 4 + wave;
    if (n >= NN) return;
    // does this node appear in the seed list? (4 entries per lane covers all 256)
    unsigned m = 0;
    #pragma unroll
    for (int e = lane; e < CC * SS; e += 64)
        if (sd[e] == n) m |= 1u << (e / SS);
    for (int o = 32; o > 0; o >>= 1) m |= __shfl_xor(m, o, 64);
    if (lane == 0) {
        known[n] = m ? 0 : INF_STAMP;   // seeds known since iteration 0
        cate[n] = m;
        nbr[n] = 0;
    }
}

// ------------- fused: memory step (blocks 0..15) + edge pass (rest, grid-stride) -------------
// edge pass is INCREMENTAL (verified passing in R8): only nodes that became known
// exactly at iteration t propagate; their cate bits are final by then, and nbr is
// a monotone OR-accumulator, so the union over iterations equals the full rescan.

__global__ __launch_bounds__(256)
void k_memedge(const float* __restrict__ es, const float* __restrict__ Wm,
               const int* __restrict__ seeds, const int* __restrict__ last,
               double* __restrict__ hx, double* __restrict__ hxn,
               float* __restrict__ out, int* __restrict__ cnt,
               const int* __restrict__ edge, const unsigned* __restrict__ cate,
               const int* __restrict__ known, unsigned* __restrict__ nbr, int t) {
    __shared__ float  inp[KK][DD + 1];   // pad: conflict-free column reads
    __shared__ int    rowS[KK];
    __shared__ double q[DD];
    __shared__ double lg[KK];
    __shared__ double sr[KK];
    __shared__ double pre[DD];
    __shared__ double red[DD];
    int tid = threadIdx.x;

    if (blockIdx.x >= CC) {
        // ---- edge branch: nbr[dst] |= cate[src] for newly-known src only ----
        for (long e = (long)(blockIdx.x - CC) * 256 + tid; e < EE;
             e += (long)EBLK * 256) {
            int s = edge[e];
            if (known[s] == t) {                 // stamp==t: became known entering iter t
                unsigned m = cate[s];            // final bits, nonzero by construction
                atomicOr(&nbr[edge[EE + e]], m);
            }
        }
        return;
    }

    // ---- memory-step branch (block-uniform; barriers legal) ----
    int c = blockIdx.x;
    if (tid == 0) cnt[c * CNT_STRIDE] = 0;     // fused counter reset
    int k = (t == 0) ? SS : KK;
    if (tid < KK) {
        lg[tid] = -1.0e308;
        if (tid < k) rowS[tid] = (t == 0) ? seeds[c * SS + tid] : last[c * KK + tid];
    }
    __syncthreads();
    for (int i = tid; i < k * DD; i += 256)
        inp[i >> 7][i & 127] = es[(long)rowS[i >> 7] * DD + (i & 127)];
    __syncthreads();
    if (tid < DD) {
        if (t == 0) {
            double s = 0;
            for (int j = 0; j < k; ++j) s += (double)inp[j][tid];
            q[tid] = s / (double)k;
        } else {
            q[tid] = hx[c * DD + tid];
        }
    }
    __syncthreads();
    if (tid < k) {
        // 4-way split accumulators: chain depth 128 -> 32 (fixed combine order)
        double s0 = 0, s1 = 0, s2 = 0, s3 = 0;
        for (int i = 0; i < DD; i += 4) {
            s0 += (double)inp[tid][i + 0] * q[i + 0];
            s1 += (double)inp[tid][i + 1] * q[i + 1];
            s2 += (double)inp[tid][i + 2] * q[i + 2];
            s3 += (double)inp[tid][i + 3] * q[i + 3];
        }
        lg[tid] = ((s0 + s1) + (s2 + s3)) / sqrt((double)DD);
    }
    __syncthreads();
    if (tid < KK) sr[tid] = lg[tid];
    __syncthreads();
    for (int st = 32; st > 0; st >>= 1) {
        if (tid < st) sr[tid] = fmax(sr[tid], sr[tid + st]);
        __syncthreads();
    }
    double mx = sr[0];
    __syncthreads();
    if (tid < KK) {
        double e = (tid < k) ? exp(lg[tid] - mx) : 0.0;
        lg[tid] = e; sr[tid] = e;
    }
    __syncthreads();
    for (int st = 32; st > 0; st >>= 1) {
        if (tid < st) sr[tid] += sr[tid + st];
        __syncthreads();
    }
    double sm = sr[0];
    __syncthreads();
    if (tid < KK) lg[tid] /= sm;
    __syncthreads();
    if (tid < DD) {
        double c0 = 0, c1 = 0, c2 = 0, c3 = 0;   // k is 16 or 64: multiple of 4
        for (int j = 0; j < k; j += 4) {
            c0 += lg[j + 0] * (double)inp[j + 0][tid];
            c1 += lg[j + 1] * (double)inp[j + 1][tid];
            c2 += lg[j + 2] * (double)inp[j + 2][tid];
            c3 += lg[j + 3] * (double)inp[j + 3][tid];
        }
        double ctx = (c0 + c1) + (c2 + c3);
        pre[tid] = (t == 0) ? ctx : (ctx + q[tid]);
    }
    __syncthreads();
    double h = 0;
    if (tid < DD) {
        double h0 = 0, h1 = 0, h2 = 0, h3 = 0;
        for (int i = 0; i < DD; i += 4) {
            h0 += pre[i + 0] * (double)Wm[(i + 0) * DD + tid];
            h1 += pre[i + 1] * (double)Wm[(i + 1) * DD + tid];
            h2 += pre[i + 2] * (double)Wm[(i + 2) * DD + tid];
            h3 += pre[i + 3] * (double)Wm[(i + 3) * DD + tid];
        }
        h = tanh((h0 + h1) + (h2 + h3));
        red[tid] = h * h;
    }
    __syncthreads();
    for (int st = 64; st > 0; st >>= 1) {
        if (tid < st) red[tid] += red[tid + st];
        __syncthreads();
    }
    if (tid < DD) {
        double inv = 1.0 / (sqrt(red[0]) + 1e-8);
        hx[c * DD + tid] = h;
        hxn[c * DD + tid] = h * inv;
        out[2 * NIT * CC * KK + t * CC * DD + c * DD + tid] = (float)h;  // hxes
    }
}

// ---------- candidate scoring: block-aggregated, thread-per-pair, norm fused ----------
// 16 split accumulators (component x parity): dFMA chain depth 64 -> 16.

__global__ __launch_bounds__(256)
void k_cand(const float* __restrict__ es,
            const int* __restrict__ known, const unsigned* __restrict__ nbr,
            const double* __restrict__ hxn,
            int* __restrict__ cnt, int* __restrict__ cidx,
            ull* __restrict__ ckey, int cap, int t) {
    __shared__ int    pair[256 * 16];
    __shared__ short  prank[256 * 16];
    __shared__ double hxnL[CC * 129];
    __shared__ int    lcnt[CC];
    __shared__ int    base[CC];
    __shared__ int    npair;
    int tid = threadIdx.x;

    for (int i = tid; i < CC * DD; i += 256)
        hxnL[(i >> 7) * 129 + (i & 127)] = hxn[i];
    if (tid < CC) lcnt[tid] = 0;
    if (tid == 0) npair = 0;
    __syncthreads();

    int n = blockIdx.x * 256 + tid;
    unsigned m = 0;
    if (n < NN && known[n] > t) m = nbr[n];   // stamp > t  <=>  unknown at iter t
    while (m) {
        int c = __ffs(m) - 1;
        m &= m - 1;
        int r = atomicAdd(&lcnt[c], 1);
        int p = atomicAdd(&npair, 1);
        pair[p] = (n << 4) | c;
        prank[p] = (short)r;
    }
    __syncthreads();

    if (tid < CC && lcnt[tid] > 0)
        base[tid] = atomicAdd(&cnt[tid * CNT_STRIDE], lcnt[tid]);
    __syncthreads();

    int np = npair;
    for (int t2 = tid; t2 < np; t2 += 256) {
        int pk = pair[t2];
        int nn = pk >> 4, c = pk & 15;
        const float4* row = (const float4*)(es + (long)nn * DD);
        const double* h = &hxnL[c * 129];
        double sx0 = 0, sy0 = 0, sz0 = 0, sw0 = 0;
        double sx1 = 0, sy1 = 0, sz1 = 0, sw1 = 0;
        double px0 = 0, py0 = 0, pz0 = 0, pw0 = 0;
        double px1 = 0, py1 = 0, pz1 = 0, pw1 = 0;
        #pragma unroll
        for (int i = 0; i < 32; i += 2) {
            float4 v = row[i];
            float4 u = row[i + 1];
            double vx = v.x, vy = v.y, vz = v.z, vw = v.w;
            double ux = u.x, uy = u.y, uz = u.z, uw = u.w;
            sx0 += vx * h[4 * i + 0];  sy0 += vy * h[4 * i + 1];
            sz0 += vz * h[4 * i + 2];  sw0 += vw * h[4 * i + 3];
            sx1 += ux * h[4 * i + 4];  sy1 += uy * h[4 * i + 5];
            sz1 += uz * h[4 * i + 6];  sw1 += uw * h[4 * i + 7];
            px0 += vx * vx;  py0 += vy * vy;  pz0 += vz * vz;  pw0 += vw * vw;
            px1 += ux * ux;  py1 += uy * uy;  pz1 += uz * uz;  pw1 += uw * uw;
        }
        double s  = (((sx0 + sy0) + (sz0 + sw0)) + ((sx1 + sy1) + (sz1 + sw1)));
        double p2 = (((px0 + py0) + (pz0 + pw0)) + ((px1 + py1) + (pz1 + pw1)));
        int pos = base[c] + (int)prank[t2];
        if (pos < cap) {
            cidx[(long)c * cap + pos] = nn;
            ckey[(long)c * cap + pos] = ordkey(s / (sqrt(p2) + 1e-8));
        }
    }
}

// ---------- stage A: per-slice exact top-64 (in-wave sorts + in-wave merge tree) ----------

__global__ __launch_bounds__(256)
void k_top(const int* __restrict__ cnt, const int* __restrict__ cidx,
           const ull* __restrict__ ckey, int cap,
           ull* __restrict__ tkey, int* __restrict__ tnode) {
    __shared__ ull ks[SLMAX];
    __shared__ int ns[SLMAX];
    int c = blockIdx.x / NB, b = blockIdx.x % NB;
    int tid = threadIdx.x, wave = tid >> 6, lane = tid & 63;
    int count = min(cnt[c * CNT_STRIDE], cap);
    int per = (count + NB - 1) / NB;
    int start = b * per;
    int m = min(per, count - start);
    int sl = 64;
    while (sl < per) sl <<= 1;
    int nruns = sl >> 6;
    // sort each 64-run inside one wave (registers, no barriers)
    for (int r = wave; r < nruns; r += 4) {
        int i = (r << 6) + lane;
        ull k; int n;
        if (i < m) { k = ckey[(long)c * cap + start + i]; n = cidx[(long)c * cap + start + i]; }
        else       { k = 0ULL; n = 0x7FFFFFFF; }
        wsort64(k, n, lane);
        ks[i] = k; ns[i] = n;
    }
    __syncthreads();
    // merge tree: each pair handled by one wave; winner written over run A
    for (int step = 1; step < nruns; step <<= 1) {
        int npair2 = nruns / (2 * step);
        for (int pr = wave; pr < npair2; pr += 4) {
            int ra = pr * 2 * step, rb = ra + step;
            ull ka = ks[(ra << 6) + lane];       int na = ns[(ra << 6) + lane];
            ull kb = ks[(rb << 6) + 63 - lane];  int nb2 = ns[(rb << 6) + 63 - lane];
            if (gt(kb, nb2, ka, na)) { ka = kb; na = nb2; }   // bitonic split -> winners
            wmerge64(ka, na, lane);
            ks[(ra << 6) + lane] = ka; ns[(ra << 6) + lane] = na;
        }
        __syncthreads();
    }
    if (tid < KK) {
        tkey[(long)c * MM + b * KK + tid] = ks[tid];
        tnode[(long)c * MM + b * KK + tid] = ns[tid];
    }
}

// ---------- stage B: merge 32 sorted runs -> top-64, apply updates + outputs (fused) ----------

__global__ __launch_bounds__(256)
void k_mergeupd(const int* __restrict__ cnt,
                const ull* __restrict__ tkey, const int* __restrict__ tnode,
                int* __restrict__ known, const unsigned* __restrict__ nbr,
                unsigned* __restrict__ cate, int* __restrict__ last,
                float* __restrict__ out, int cap, int t) {
    __shared__ ull ks[MM];
    __shared__ int ns[MM];
    int c = blockIdx.x, tid = threadIdx.x, wave = tid >> 6, lane = tid & 63;
    for (int i = tid; i < MM; i += 256) {
        ks[i] = tkey[(long)c * MM + i];
        ns[i] = tnode[(long)c * MM + i];
    }
    __syncthreads();
    for (int step = 1; step < NB; step <<= 1) {
        int npair2 = NB / (2 * step);
        for (int pr = wave; pr < npair2; pr += 4) {
            int ra = pr * 2 * step, rb = ra + step;
            ull ka = ks[(ra << 6) + lane];       int na = ns[(ra << 6) + lane];
            ull kb = ks[(rb << 6) + 63 - lane];  int nb2 = ns[(rb << 6) + 63 - lane];
            if (gt(kb, nb2, ka, na)) { ka = kb; na = nb2; }
            wmerge64(ka, na, lane);
            ks[(ra << 6) + lane] = ka; ns[(ra << 6) + lane] = na;
        }
        __syncthreads();
    }
    int count = min(cnt[c * CNT_STRIDE], cap);
    int nsel = min(count, KK);
    if (tid < KK && tid < nsel) {
        int n = ns[tid];
        out[t * CC * KK + c * KK + tid] = (float)keyord(ks[tid]);     // outs
        out[NIT * CC * KK + t * CC * KK + c * KK + tid] = (float)n;   // exps
        last[c * KK + tid] = n;
        known[n] = t + 1;               // stamp: invisible to this iteration's tests
        atomicOr(&cate[n], 1u << c);
    }
    // fill path (fewer valid than K): lowest-index invalid nodes, prob=-1e9.
    // stamp test (known[n] <= t) sees only pre-iteration state -> race-free vs
    // concurrent t+1 stamps from other classes (matches reference semantics).
    if (tid == 0 && nsel < KK) {
        int r = nsel;
        for (int n = 0; n < NN && r < KK; ++n) {
            bool valid = ((nbr[n] >> c) & 1u) && (known[n] > t);
            if (!valid) {
                out[t * CC * KK + c * KK + r] = -1e9f;
                out[NIT * CC * KK + t * CC * KK + c * KK + r] = (float)n;
                last[c * KK + r] = n;
                known[n] = t + 1;
                atomicOr(&cate[n], 1u << c);
                ++r;
            }
        }
    }
}

// -------------------- host launcher: 17 launches total --------------------

extern "C" void kernel_launch(void* const* d_in, const int* in_sizes, int n_in,
                              void* d_out, int out_size, void* d_ws, size_t ws_size,
                              hipStream_t stream) {
    const float* es    = (const float*)d_in[0];
    const int*   edge  = (const int*)d_in[1];
    const int*   seeds = (const int*)d_in[2];
    const float* W     = (const float*)d_in[3];
    float* out = (float*)d_out;

    char* p = (char*)d_ws;
    auto alloc = [&](size_t bytes) -> char* {
        char* r = p;
        p += (bytes + 255) & ~(size_t)255;
        return r;
    };
    int*      known    = (int*)alloc((size_t)NN * 4);
    unsigned* cate     = (unsigned*)alloc((size_t)NN * 4);
    unsigned* nbr      = (unsigned*)alloc((size_t)NN * 4);
    double*   hx       = (double*)alloc(CC * DD * 8);
    double*   hxn      = (double*)alloc(CC * DD * 8);
    int*      last     = (int*)alloc(CC * KK * 4);
    int*      cnt      = (int*)alloc(CC * CNT_STRIDE * 4);
    ull*      tkey     = (ull*)alloc((size_t)CC * MM * 8);
    int*      tnode    = (int*)alloc((size_t)CC * MM * 4);
    size_t used = (size_t)(p - (char*)d_ws);
    size_t rem = (ws_size > used + 8192) ? (ws_size - used - 8192) : 0;
    long capl = (long)(rem / (CC * 12));
    if (capl > NN) capl = NN;
    if (capl < 1) capl = 1;
    int cap = (int)capl;
    int*    cidx = (int*)alloc((size_t)CC * cap * 4);
    ull*    ckey = (ull*)alloc((size_t)CC * cap * 8);

    k_init<<<(NN + 3) / 4, 256, 0, stream>>>(seeds, known, cate, nbr);

    for (int t = 0; t < NIT; ++t) {
        k_memedge<<<CC + EBLK, 256, 0, stream>>>(es, W, seeds, last, hx, hxn, out,
                                                 cnt, edge, cate, known, nbr, t);
        k_cand<<<(NN + 255) / 256, 256, 0, stream>>>(es, known, nbr, hxn,
                                                     cnt, cidx, ckey, cap, t);
        k_top<<<CC * NB, 256, 0, stream>>>(cnt, cidx, ckey, cap, tkey, tnode);
        k_mergeupd<<<CC, 256, 0, stream>>>(cnt, tkey, tnode, known, nbr,
                                           cate, last, out, cap, t);
    }
}